// Round 1
// baseline (1726.101 us; speedup 1.0000x reference)
//
#include <hip/hip_runtime.h>
#include <hip/hip_bf16.h>

#define NNODES 50000
#define NEDGES 800000
#define RSQRT_D 0.17677669529663687f  // 1/sqrt(32)

// ---------------------------------------------------------------------------
// Kernel 1: y0 = [x, x*t] (N x 256); Q/K/V = y0 @ W* + b* (N x 128 each);
// S = y0 @ Wskip + bskip (N x 32).  64x64 tile, 4x4 micro-tile per thread.
// grid = (ceil(N/64), 7): col tiles 0-1 Q, 2-3 K, 4-5 V, 6 skip(32 valid).
// ---------------------------------------------------------------------------
__global__ __launch_bounds__(256) void gemm_qkvs(
    const float* __restrict__ x, const float* __restrict__ t,
    const float* __restrict__ Wq, const float* __restrict__ bq,
    const float* __restrict__ Wk, const float* __restrict__ bk,
    const float* __restrict__ Wv, const float* __restrict__ bv,
    const float* __restrict__ Wskip, const float* __restrict__ bskip,
    float* __restrict__ Q, float* __restrict__ K, float* __restrict__ V,
    float* __restrict__ S)
{
    __shared__ float y0s[32][68];   // [k][node], padded stride 68 (16B-aligned rows)
    __shared__ float Ws[32][64];    // [k][col]

    const int n0 = blockIdx.x * 64;
    const int tilec = blockIdx.y;            // 0..6
    const int which = (tilec * 64) >> 7;     // 0,0,1,1,2,2,3
    const int colbase = tilec * 64 - which * 128;  // 0,64,0,64,0,64,0

    const float* W; const float* bias; float* Out; int ldw, outw;
    if (which == 0)      { W = Wq;    bias = bq;    Out = Q; ldw = 128; outw = 128; }
    else if (which == 1) { W = Wk;    bias = bk;    Out = K; ldw = 128; outw = 128; }
    else if (which == 2) { W = Wv;    bias = bv;    Out = V; ldw = 128; outw = 128; }
    else                 { W = Wskip; bias = bskip; Out = S; ldw = 32;  outw = 32;  }

    const int tid = threadIdx.x;
    const int tx = tid & 15;      // col group (4 cols)
    const int ty = tid >> 4;      // node group (4 nodes)

    float acc[4][4] = {};

    // y0 loader mapping: each thread loads 2 float4 along k for one node
    const int nl = tid >> 2;             // 0..63
    const int kq = (tid & 3) * 4;        // 0,4,8,12
    const int ng = n0 + nl;
    const float tval = (ng < NNODES) ? t[ng] : 0.f;

    for (int kt = 0; kt < 8; ++kt) {
        const int k0 = kt * 32;
        float4 va = make_float4(0, 0, 0, 0), vb = va;
        if (ng < NNODES) {
            const int kk = (k0 < 128) ? k0 : (k0 - 128);
            const float* xr = x + (size_t)ng * 128 + kk;
            va = *(const float4*)(xr + kq);
            vb = *(const float4*)(xr + kq + 16);
            if (k0 >= 128) {
                va.x *= tval; va.y *= tval; va.z *= tval; va.w *= tval;
                vb.x *= tval; vb.y *= tval; vb.z *= tval; vb.w *= tval;
            }
        }
        __syncthreads();  // previous iter's LDS reads done
        y0s[kq + 0][nl] = va.x; y0s[kq + 1][nl] = va.y;
        y0s[kq + 2][nl] = va.z; y0s[kq + 3][nl] = va.w;
        y0s[kq + 16][nl] = vb.x; y0s[kq + 17][nl] = vb.y;
        y0s[kq + 18][nl] = vb.z; y0s[kq + 19][nl] = vb.w;

        {   // W tile: Ws[k][c]
            const int kw = tid >> 3;          // 0..31
            const int c0 = (tid & 7) * 4;     // 0..28
            #pragma unroll
            for (int rep = 0; rep < 2; ++rep) {
                const int c = c0 + rep * 32;
                const int gc = colbase + c;
                float4 w4 = make_float4(0, 0, 0, 0);
                if (gc < outw) w4 = *(const float4*)(W + (size_t)(k0 + kw) * ldw + gc);
                Ws[kw][c + 0] = w4.x; Ws[kw][c + 1] = w4.y;
                Ws[kw][c + 2] = w4.z; Ws[kw][c + 3] = w4.w;
            }
        }
        __syncthreads();

        #pragma unroll
        for (int kk = 0; kk < 32; ++kk) {
            const float4 a4 = *(const float4*)&y0s[kk][ty * 4];
            const float4 b4 = *(const float4*)&Ws[kk][tx * 4];
            acc[0][0] += a4.x * b4.x; acc[0][1] += a4.x * b4.y;
            acc[0][2] += a4.x * b4.z; acc[0][3] += a4.x * b4.w;
            acc[1][0] += a4.y * b4.x; acc[1][1] += a4.y * b4.y;
            acc[1][2] += a4.y * b4.z; acc[1][3] += a4.y * b4.w;
            acc[2][0] += a4.z * b4.x; acc[2][1] += a4.z * b4.y;
            acc[2][2] += a4.z * b4.z; acc[2][3] += a4.z * b4.w;
            acc[3][0] += a4.w * b4.x; acc[3][1] += a4.w * b4.y;
            acc[3][2] += a4.w * b4.z; acc[3][3] += a4.w * b4.w;
        }
    }

    const int cglob = colbase + tx * 4;
    if (cglob < outw) {
        const float4 bb = *(const float4*)(bias + cglob);
        #pragma unroll
        for (int i = 0; i < 4; ++i) {
            const int n = n0 + ty * 4 + i;
            if (n < NNODES) {
                float4 o;
                o.x = acc[i][0] + bb.x; o.y = acc[i][1] + bb.y;
                o.z = acc[i][2] + bb.z; o.w = acc[i][3] + bb.w;
                *(float4*)(Out + (size_t)n * outw + cglob) = o;
            }
        }
    }
}

// ---------------------------------------------------------------------------
// Kernel 2: per edge (32 lanes/edge, 8 edges per 256-block):
//   e = ew*We + be; alpha_h = dot(q[dst],k[src]+e)_h / sqrt(D); p = exp(alpha)
//   atomicAdd denom[dst][h] += p ; atomicAdd agg[dst][h][d] += p*(v[src]+e)
// (no max-subtraction: alpha is O(1), softmax is shift-invariant)
// ---------------------------------------------------------------------------
__global__ __launch_bounds__(256) void edge_pass(
    const int* __restrict__ ei, const float* __restrict__ ew,
    const float* __restrict__ We, const float* __restrict__ be,
    const float* __restrict__ Q, const float* __restrict__ K,
    const float* __restrict__ V,
    float* __restrict__ agg, float* __restrict__ denom)
{
    const int tid = threadIdx.x;
    const int eg = blockIdx.x * 8 + (tid >> 5);
    if (eg >= NEDGES) return;
    const int l = tid & 31;           // lane within edge-group: 4 dims each

    const int src = ei[eg];
    const int dst = ei[NEDGES + eg];
    const float w = ew[eg];

    const float4 We4 = *(const float4*)(We + l * 4);
    const float4 be4 = *(const float4*)(be + l * 4);
    float4 e4;
    e4.x = w * We4.x + be4.x; e4.y = w * We4.y + be4.y;
    e4.z = w * We4.z + be4.z; e4.w = w * We4.w + be4.w;

    const float4 q4 = *(const float4*)(Q + (size_t)dst * 128 + l * 4);
    const float4 k4 = *(const float4*)(K + (size_t)src * 128 + l * 4);
    const float4 v4 = *(const float4*)(V + (size_t)src * 128 + l * 4);

    float part = q4.x * (k4.x + e4.x) + q4.y * (k4.y + e4.y)
               + q4.z * (k4.z + e4.z) + q4.w * (k4.w + e4.w);
    part += __shfl_xor(part, 1);
    part += __shfl_xor(part, 2);
    part += __shfl_xor(part, 4);      // now full head-dot in all 8 lanes of group
    const float alpha = part * RSQRT_D;
    const float p = __expf(alpha);

    if ((l & 7) == 0) atomicAdd(denom + (size_t)dst * 4 + (l >> 3), p);

    float* ag = agg + (size_t)dst * 128 + l * 4;
    atomicAdd(ag + 0, p * (v4.x + e4.x));
    atomicAdd(ag + 1, p * (v4.y + e4.y));
    atomicAdd(ag + 2, p * (v4.z + e4.z));
    atomicAdd(ag + 3, p * (v4.w + e4.w));
}

// ---------------------------------------------------------------------------
// Kernel 3: per node: g = mean_h(agg_h/(denom_h+1e-16)); y = tanh(g + skip);
// z = tanh(y @ Wmlp + bmlp); out = x*z[:,:128] + z[:,128:]
// 64 nodes per block; Wmlp (32x256) staged in LDS.
// ---------------------------------------------------------------------------
__global__ __launch_bounds__(256) void node_pass(
    const float* __restrict__ x,
    const float* __restrict__ agg, const float* __restrict__ denom,
    const float* __restrict__ S,
    const float* __restrict__ Wmlp, const float* __restrict__ bmlp,
    float* __restrict__ out)
{
    __shared__ float Wm[32 * 256];
    __shared__ float bm[256];
    __shared__ float yl[64 * 32];

    const int tid = threadIdx.x;
    for (int i = tid; i < 2048; i += 256)
        *(float4*)&Wm[i * 4] = *(const float4*)(Wmlp + i * 4);
    if (tid < 64)
        *(float4*)&bm[tid * 4] = *(const float4*)(bmlp + tid * 4);

    const int n0 = blockIdx.x * 64;

    for (int idx = tid; idx < 64 * 32; idx += 256) {
        const int nl = idx >> 5, d = idx & 31;
        const int n = n0 + nl;
        float yv = 0.f;
        if (n < NNODES) {
            float g = 0.f;
            #pragma unroll
            for (int h = 0; h < 4; ++h)
                g += agg[(size_t)n * 128 + h * 32 + d] / (denom[(size_t)n * 4 + h] + 1e-16f);
            yv = tanhf(0.25f * g + S[(size_t)n * 32 + d]);
        }
        yl[idx] = yv;
    }
    __syncthreads();

    for (int idx = tid; idx < 64 * 128; idx += 256) {
        const int nl = idx >> 7, c = idx & 127;
        const int n = n0 + nl;
        if (n >= NNODES) continue;
        float s1 = bm[c], s2 = bm[c + 128];
        const float* yrow = &yl[nl * 32];
        #pragma unroll
        for (int d = 0; d < 32; ++d) {
            const float yv = yrow[d];
            s1 += yv * Wm[d * 256 + c];
            s2 += yv * Wm[d * 256 + c + 128];
        }
        out[(size_t)n * 128 + c] = x[(size_t)n * 128 + c] * tanhf(s1) + tanhf(s2);
    }
}

// ---------------------------------------------------------------------------
extern "C" void kernel_launch(void* const* d_in, const int* in_sizes, int n_in,
                              void* d_out, int out_size, void* d_ws, size_t ws_size,
                              hipStream_t stream) {
    const float* x     = (const float*)d_in[0];
    const float* t     = (const float*)d_in[1];
    const int*   ei    = (const int*)  d_in[2];
    const float* ew    = (const float*)d_in[3];
    const float* Wq    = (const float*)d_in[4];
    const float* bq    = (const float*)d_in[5];
    const float* Wk    = (const float*)d_in[6];
    const float* bk    = (const float*)d_in[7];
    const float* Wv    = (const float*)d_in[8];
    const float* bv    = (const float*)d_in[9];
    const float* We    = (const float*)d_in[10];
    const float* be    = (const float*)d_in[11];
    const float* Wskip = (const float*)d_in[12];
    const float* bskip = (const float*)d_in[13];
    const float* Wmlp  = (const float*)d_in[14];
    const float* bmlp  = (const float*)d_in[15];

    float* ws = (float*)d_ws;
    float* Q     = ws;                      // N*128
    float* K     = Q + (size_t)NNODES * 128;
    float* V     = K + (size_t)NNODES * 128;
    float* S     = V + (size_t)NNODES * 128;   // N*32
    float* denom = S + (size_t)NNODES * 32;    // N*4
    float* agg   = denom + (size_t)NNODES * 4; // N*128

    // zero denom+agg (contiguous)
    hipMemsetAsync(denom, 0, (size_t)NNODES * (4 + 128) * sizeof(float), stream);

    dim3 g1((NNODES + 63) / 64, 7);
    gemm_qkvs<<<g1, 256, 0, stream>>>(x, t, Wq, bq, Wk, bk, Wv, bv,
                                      Wskip, bskip, Q, K, V, S);

    edge_pass<<<NEDGES / 8, 256, 0, stream>>>(ei, ew, We, be, Q, K, V, agg, denom);

    node_pass<<<(NNODES + 63) / 64, 256, 0, stream>>>(x, agg, denom, S, Wmlp, bmlp,
                                                      (float*)d_out);
}

// Round 2
// 621.311 us; speedup vs baseline: 2.7782x; 2.7782x over previous
//
#include <hip/hip_runtime.h>
#include <hip/hip_bf16.h>

#define NNODES 50000
#define NEDGES 800000
#define RSQRT_D 0.17677669529663687f  // 1/sqrt(32)

// ---------------------------------------------------------------------------
// Kernel 1: y0 = [x, x*t] (N x 256); Q/K/V = y0 @ W* + b* (N x 128 each);
// S = y0 @ Wskip + bskip (N x 32).  64x64 tile, 4x4 micro-tile per thread.
// ---------------------------------------------------------------------------
__global__ __launch_bounds__(256) void gemm_qkvs(
    const float* __restrict__ x, const float* __restrict__ t,
    const float* __restrict__ Wq, const float* __restrict__ bq,
    const float* __restrict__ Wk, const float* __restrict__ bk,
    const float* __restrict__ Wv, const float* __restrict__ bv,
    const float* __restrict__ Wskip, const float* __restrict__ bskip,
    float* __restrict__ Q, float* __restrict__ K, float* __restrict__ V,
    float* __restrict__ S)
{
    __shared__ float y0s[32][68];
    __shared__ float Ws[32][64];

    const int n0 = blockIdx.x * 64;
    const int tilec = blockIdx.y;
    const int which = (tilec * 64) >> 7;
    const int colbase = tilec * 64 - which * 128;

    const float* W; const float* bias; float* Out; int ldw, outw;
    if (which == 0)      { W = Wq;    bias = bq;    Out = Q; ldw = 128; outw = 128; }
    else if (which == 1) { W = Wk;    bias = bk;    Out = K; ldw = 128; outw = 128; }
    else if (which == 2) { W = Wv;    bias = bv;    Out = V; ldw = 128; outw = 128; }
    else                 { W = Wskip; bias = bskip; Out = S; ldw = 32;  outw = 32;  }

    const int tid = threadIdx.x;
    const int tx = tid & 15;
    const int ty = tid >> 4;

    float acc[4][4] = {};

    const int nl = tid >> 2;
    const int kq = (tid & 3) * 4;
    const int ng = n0 + nl;
    const float tval = (ng < NNODES) ? t[ng] : 0.f;

    for (int kt = 0; kt < 8; ++kt) {
        const int k0 = kt * 32;
        float4 va = make_float4(0, 0, 0, 0), vb = va;
        if (ng < NNODES) {
            const int kk = (k0 < 128) ? k0 : (k0 - 128);
            const float* xr = x + (size_t)ng * 128 + kk;
            va = *(const float4*)(xr + kq);
            vb = *(const float4*)(xr + kq + 16);
            if (k0 >= 128) {
                va.x *= tval; va.y *= tval; va.z *= tval; va.w *= tval;
                vb.x *= tval; vb.y *= tval; vb.z *= tval; vb.w *= tval;
            }
        }
        __syncthreads();
        y0s[kq + 0][nl] = va.x; y0s[kq + 1][nl] = va.y;
        y0s[kq + 2][nl] = va.z; y0s[kq + 3][nl] = va.w;
        y0s[kq + 16][nl] = vb.x; y0s[kq + 17][nl] = vb.y;
        y0s[kq + 18][nl] = vb.z; y0s[kq + 19][nl] = vb.w;

        {
            const int kw = tid >> 3;
            const int c0 = (tid & 7) * 4;
            #pragma unroll
            for (int rep = 0; rep < 2; ++rep) {
                const int c = c0 + rep * 32;
                const int gc = colbase + c;
                float4 w4 = make_float4(0, 0, 0, 0);
                if (gc < outw) w4 = *(const float4*)(W + (size_t)(k0 + kw) * ldw + gc);
                Ws[kw][c + 0] = w4.x; Ws[kw][c + 1] = w4.y;
                Ws[kw][c + 2] = w4.z; Ws[kw][c + 3] = w4.w;
            }
        }
        __syncthreads();

        #pragma unroll
        for (int kk = 0; kk < 32; ++kk) {
            const float4 a4 = *(const float4*)&y0s[kk][ty * 4];
            const float4 b4 = *(const float4*)&Ws[kk][tx * 4];
            acc[0][0] += a4.x * b4.x; acc[0][1] += a4.x * b4.y;
            acc[0][2] += a4.x * b4.z; acc[0][3] += a4.x * b4.w;
            acc[1][0] += a4.y * b4.x; acc[1][1] += a4.y * b4.y;
            acc[1][2] += a4.y * b4.z; acc[1][3] += a4.y * b4.w;
            acc[2][0] += a4.z * b4.x; acc[2][1] += a4.z * b4.y;
            acc[2][2] += a4.z * b4.z; acc[2][3] += a4.z * b4.w;
            acc[3][0] += a4.w * b4.x; acc[3][1] += a4.w * b4.y;
            acc[3][2] += a4.w * b4.z; acc[3][3] += a4.w * b4.w;
        }
    }

    const int cglob = colbase + tx * 4;
    if (cglob < outw) {
        const float4 bb = *(const float4*)(bias + cglob);
        #pragma unroll
        for (int i = 0; i < 4; ++i) {
            const int n = n0 + ty * 4 + i;
            if (n < NNODES) {
                float4 o;
                o.x = acc[i][0] + bb.x; o.y = acc[i][1] + bb.y;
                o.z = acc[i][2] + bb.z; o.w = acc[i][3] + bb.w;
                *(float4*)(Out + (size_t)n * outw + cglob) = o;
            }
        }
    }
}

// ---------------------------------------------------------------------------
// CSR build: histogram over dst, exclusive scan, scatter (src, w) by dst.
// ---------------------------------------------------------------------------
__global__ __launch_bounds__(256) void hist_kernel(
    const int* __restrict__ ei, int* __restrict__ cnt)
{
    const int e = blockIdx.x * 256 + threadIdx.x;
    if (e < NEDGES) atomicAdd(&cnt[ei[NEDGES + e]], 1);
}

#define CHUNK 49  // 49*1024 = 50176 >= 50000
__global__ __launch_bounds__(1024) void scan_kernel(
    const int* __restrict__ cnt, int* __restrict__ off, int* __restrict__ cursor)
{
    __shared__ int part[1024];
    const int t = threadIdx.x;
    const int base = t * CHUNK;
    int s = 0;
    #pragma unroll 7
    for (int i = 0; i < CHUNK; ++i) {
        const int idx = base + i;
        if (idx < NNODES) s += cnt[idx];
    }
    part[t] = s;
    __syncthreads();
    // Hillis-Steele inclusive scan over 1024 partials
    for (int d = 1; d < 1024; d <<= 1) {
        const int v = part[t];
        const int o = (t >= d) ? part[t - d] : 0;
        __syncthreads();
        part[t] = v + o;
        __syncthreads();
    }
    int run = (t == 0) ? 0 : part[t - 1];
    #pragma unroll 7
    for (int i = 0; i < CHUNK; ++i) {
        const int idx = base + i;
        if (idx < NNODES) {
            off[idx] = run;
            cursor[idx] = run;
            run += cnt[idx];
        }
    }
    if (t == 1023) off[NNODES] = run;
}

__global__ __launch_bounds__(256) void scatter_kernel(
    const int* __restrict__ ei, const float* __restrict__ ew,
    int* __restrict__ cursor, int* __restrict__ esrc, float* __restrict__ ews)
{
    const int e = blockIdx.x * 256 + threadIdx.x;
    if (e >= NEDGES) return;
    const int src = ei[e];
    const int dst = ei[NEDGES + e];
    const int pos = atomicAdd(&cursor[dst], 1);
    esrc[pos] = src;
    ews[pos] = ew[e];
}

// ---------------------------------------------------------------------------
// Aggregation: one 32-lane group per node (8 nodes / 256-block), registers
// accumulate p*(v+e); fused softmax-normalize + head-mean -> G (N x 32).
// ---------------------------------------------------------------------------
__global__ __launch_bounds__(256) void agg_pass(
    const int* __restrict__ off, const int* __restrict__ esrc,
    const float* __restrict__ ews,
    const float* __restrict__ We, const float* __restrict__ be,
    const float* __restrict__ Q, const float* __restrict__ K,
    const float* __restrict__ V, float* __restrict__ G)
{
    const int tid = threadIdx.x;
    const int node = blockIdx.x * 8 + (tid >> 5);
    if (node >= NNODES) return;
    const int l = tid & 31;          // 4 dims per lane; head = l>>3

    const float4 We4 = *(const float4*)(We + l * 4);
    const float4 be4 = *(const float4*)(be + l * 4);
    const float4 q4  = *(const float4*)(Q + (size_t)node * 128 + l * 4);

    float4 acc = make_float4(0, 0, 0, 0);
    float dsum = 0.f;

    const int jb = off[node], je = off[node + 1];
    for (int j = jb; j < je; ++j) {
        const int src = esrc[j];
        const float w = ews[j];
        const float4 k4 = *(const float4*)(K + (size_t)src * 128 + l * 4);
        const float4 v4 = *(const float4*)(V + (size_t)src * 128 + l * 4);
        float4 e4;
        e4.x = w * We4.x + be4.x; e4.y = w * We4.y + be4.y;
        e4.z = w * We4.z + be4.z; e4.w = w * We4.w + be4.w;

        float part = q4.x * (k4.x + e4.x) + q4.y * (k4.y + e4.y)
                   + q4.z * (k4.z + e4.z) + q4.w * (k4.w + e4.w);
        part += __shfl_xor(part, 1);
        part += __shfl_xor(part, 2);
        part += __shfl_xor(part, 4);     // head-dot in all 8 lanes of head group
        const float p = __expf(part * RSQRT_D);
        dsum += p;
        acc.x += p * (v4.x + e4.x);
        acc.y += p * (v4.y + e4.y);
        acc.z += p * (v4.z + e4.z);
        acc.w += p * (v4.w + e4.w);
    }

    // softmax normalize (dsum identical within each 8-lane head group)
    const float inv = 1.f / (dsum + 1e-16f);
    acc.x *= inv; acc.y *= inv; acc.z *= inv; acc.w *= inv;

    // head mean: lanes l, l^8, l^16, l^24 hold the same within-head dim d
    acc.x += __shfl_xor(acc.x, 8);  acc.y += __shfl_xor(acc.y, 8);
    acc.z += __shfl_xor(acc.z, 8);  acc.w += __shfl_xor(acc.w, 8);
    acc.x += __shfl_xor(acc.x, 16); acc.y += __shfl_xor(acc.y, 16);
    acc.z += __shfl_xor(acc.z, 16); acc.w += __shfl_xor(acc.w, 16);

    if (l < 8) {
        float4 g;
        g.x = acc.x * 0.25f; g.y = acc.y * 0.25f;
        g.z = acc.z * 0.25f; g.w = acc.w * 0.25f;
        *(float4*)(G + (size_t)node * 32 + l * 4) = g;
    }
}

// ---------------------------------------------------------------------------
// Node epilogue: y = tanh(G + S); z = tanh(y @ Wmlp + bmlp);
// out = x*z[:,:128] + z[:,128:]
// ---------------------------------------------------------------------------
__global__ __launch_bounds__(256) void node_pass(
    const float* __restrict__ x,
    const float* __restrict__ G, const float* __restrict__ S,
    const float* __restrict__ Wmlp, const float* __restrict__ bmlp,
    float* __restrict__ out)
{
    __shared__ float Wm[32 * 256];
    __shared__ float bm[256];
    __shared__ float yl[64 * 32];

    const int tid = threadIdx.x;
    for (int i = tid; i < 2048; i += 256)
        *(float4*)&Wm[i * 4] = *(const float4*)(Wmlp + i * 4);
    if (tid < 64)
        *(float4*)&bm[tid * 4] = *(const float4*)(bmlp + tid * 4);

    const int n0 = blockIdx.x * 64;

    for (int idx = tid; idx < 64 * 32; idx += 256) {
        const int nl = idx >> 5, d = idx & 31;
        const int n = n0 + nl;
        float yv = 0.f;
        if (n < NNODES)
            yv = tanhf(G[(size_t)n * 32 + d] + S[(size_t)n * 32 + d]);
        yl[idx] = yv;
    }
    __syncthreads();

    for (int idx = tid; idx < 64 * 128; idx += 256) {
        const int nl = idx >> 7, c = idx & 127;
        const int n = n0 + nl;
        if (n >= NNODES) continue;
        float s1 = bm[c], s2 = bm[c + 128];
        const float* yrow = &yl[nl * 32];
        #pragma unroll
        for (int d = 0; d < 32; ++d) {
            const float yv = yrow[d];
            s1 += yv * Wm[d * 256 + c];
            s2 += yv * Wm[d * 256 + c + 128];
        }
        out[(size_t)n * 128 + c] = x[(size_t)n * 128 + c] * tanhf(s1) + tanhf(s2);
    }
}

// ---------------------------------------------------------------------------
extern "C" void kernel_launch(void* const* d_in, const int* in_sizes, int n_in,
                              void* d_out, int out_size, void* d_ws, size_t ws_size,
                              hipStream_t stream) {
    const float* x     = (const float*)d_in[0];
    const float* t     = (const float*)d_in[1];
    const int*   ei    = (const int*)  d_in[2];
    const float* ew    = (const float*)d_in[3];
    const float* Wq    = (const float*)d_in[4];
    const float* bq    = (const float*)d_in[5];
    const float* Wk    = (const float*)d_in[6];
    const float* bk    = (const float*)d_in[7];
    const float* Wv    = (const float*)d_in[8];
    const float* bv    = (const float*)d_in[9];
    const float* We    = (const float*)d_in[10];
    const float* be    = (const float*)d_in[11];
    const float* Wskip = (const float*)d_in[12];
    const float* bskip = (const float*)d_in[13];
    const float* Wmlp  = (const float*)d_in[14];
    const float* bmlp  = (const float*)d_in[15];

    float* ws = (float*)d_ws;
    float* Q    = ws;                           // N*128
    float* K    = Q + (size_t)NNODES * 128;     // N*128
    float* V    = K + (size_t)NNODES * 128;     // N*128
    float* S    = V + (size_t)NNODES * 128;     // N*32
    float* G    = S + (size_t)NNODES * 32;      // N*32
    int*   cnt    = (int*)(G + (size_t)NNODES * 32);  // N
    int*   off    = cnt + NNODES;               // N+1
    int*   cursor = off + NNODES + 1;           // N
    int*   esrc   = cursor + NNODES;            // E
    float* ews    = (float*)(esrc + NEDGES);    // E

    hipMemsetAsync(cnt, 0, (size_t)NNODES * sizeof(int), stream);

    dim3 g1((NNODES + 63) / 64, 7);
    gemm_qkvs<<<g1, 256, 0, stream>>>(x, t, Wq, bq, Wk, bk, Wv, bv,
                                      Wskip, bskip, Q, K, V, S);

    hist_kernel<<<NEDGES / 256, 256, 0, stream>>>(ei, cnt);
    scan_kernel<<<1, 1024, 0, stream>>>(cnt, off, cursor);
    scatter_kernel<<<NEDGES / 256, 256, 0, stream>>>(ei, ew, cursor, esrc, ews);

    agg_pass<<<NNODES / 8, 256, 0, stream>>>(off, esrc, ews, We, be, Q, K, V, G);

    node_pass<<<(NNODES + 63) / 64, 256, 0, stream>>>(x, G, S, Wmlp, bmlp,
                                                      (float*)d_out);
}

// Round 3
// 563.049 us; speedup vs baseline: 3.0656x; 1.1035x over previous
//
#include <hip/hip_runtime.h>
#include <hip/hip_bf16.h>

#define NNODES 50000
#define NEDGES 800000
#define RSQRT_D 0.17677669529663687f  // 1/sqrt(32)

typedef short short8 __attribute__((ext_vector_type(8)));   // 8 bf16 (4 VGPRs)
typedef float f32x4 __attribute__((ext_vector_type(4)));    // MFMA accumulator

__device__ inline unsigned short f2bf(float f) {
    union { float f; unsigned u; } v; v.f = f;
    unsigned r = (v.u + 0x7fff + ((v.u >> 16) & 1)) >> 16;   // round-to-nearest-even
    return (unsigned short)r;
}
__device__ inline float bf2f(unsigned short u) {
    union { unsigned u; float f; } v; v.u = ((unsigned)u) << 16;
    return v.f;
}

// ---------------------------------------------------------------------------
// prep_w: Wt[col][k] bf16 (col 0..415 = Q|K|V|skip), biascat[col] fp32.
// grid 416 blocks x 256 threads (block = col, thread = k).
// ---------------------------------------------------------------------------
__global__ __launch_bounds__(256) void prep_w(
    const float* __restrict__ Wq, const float* __restrict__ bq,
    const float* __restrict__ Wk, const float* __restrict__ bk,
    const float* __restrict__ Wv, const float* __restrict__ bv,
    const float* __restrict__ Wskip, const float* __restrict__ bskip,
    unsigned short* __restrict__ Wt, float* __restrict__ biascat)
{
    const int col = blockIdx.x;
    const int k = threadIdx.x;
    float v; float b;
    if (col < 128)      { v = Wq[k * 128 + col];          b = bq[col]; }
    else if (col < 256) { v = Wk[k * 128 + col - 128];    b = bk[col - 128]; }
    else if (col < 384) { v = Wv[k * 128 + col - 256];    b = bv[col - 256]; }
    else                { v = Wskip[k * 32 + col - 384];  b = bskip[col - 384]; }
    Wt[col * 256 + k] = f2bf(v);
    if (k == 0) biascat[col] = b;
}

// ---------------------------------------------------------------------------
// gemm_mfma: C[n][c] = y0[n][:] @ Wt[c][:] + bias, split-bf16 (hi+lo) MFMA.
// Block = 256 thr = 4 waves; wave handles 32 rows x all 416 cols.
// No LDS, no barriers: A-frags live in registers, B-frags read from L2-hot Wt.
// Outputs: Q bf16 [N][128], KV bf16 [N][256] (K|V), S fp32 [N][32].
// ---------------------------------------------------------------------------
__global__ __launch_bounds__(256) void gemm_mfma(
    const float* __restrict__ x, const float* __restrict__ t,
    const unsigned short* __restrict__ Wt, const float* __restrict__ biascat,
    unsigned short* __restrict__ Qb, unsigned short* __restrict__ KVb,
    float* __restrict__ S)
{
    const int tid = threadIdx.x;
    const int wave = tid >> 6;
    const int lane = tid & 63;
    const int row16 = lane & 15;
    const int quad = lane >> 4;

    const int n0 = blockIdx.x * 128 + wave * 32;
    const int rowA = n0 + row16;
    const int rowB = rowA + 16;

    short8 ahiA[8], aloA[8], ahiB[8], aloB[8];

    // Load this wave's A fragments once (y0 = [x, x*t] computed on the fly)
    #pragma unroll
    for (int kt = 0; kt < 8; ++kt) {
        const int kk = kt * 32 + quad * 8;          // 0..248, frag k-offset
        const int kx = (kk < 128) ? kk : (kk - 128);
        #pragma unroll
        for (int half = 0; half < 2; ++half) {
            const int row = half ? rowB : rowA;
            float4 f0 = make_float4(0, 0, 0, 0), f1 = f0;
            if (row < NNODES) {
                const float* xr = x + (size_t)row * 128 + kx;
                f0 = *(const float4*)xr;
                f1 = *(const float4*)(xr + 4);
                if (kk >= 128) {
                    const float tv = t[row];
                    f0.x *= tv; f0.y *= tv; f0.z *= tv; f0.w *= tv;
                    f1.x *= tv; f1.y *= tv; f1.z *= tv; f1.w *= tv;
                }
            }
            float fv[8] = { f0.x, f0.y, f0.z, f0.w, f1.x, f1.y, f1.z, f1.w };
            short8 hi, lo;
            #pragma unroll
            for (int j = 0; j < 8; ++j) {
                const unsigned short h = f2bf(fv[j]);
                hi[j] = (short)h;
                lo[j] = (short)f2bf(fv[j] - bf2f(h));
            }
            if (half) { ahiB[kt] = hi; aloB[kt] = lo; }
            else      { ahiA[kt] = hi; aloA[kt] = lo; }
        }
    }

    // Column tiles: 26 x 16 = 416 output columns
    for (int ct = 0; ct < 26; ++ct) {
        const int c = ct * 16 + row16;              // this lane's B col / D col
        f32x4 accA = {0.f, 0.f, 0.f, 0.f};
        f32x4 accB = {0.f, 0.f, 0.f, 0.f};
        #pragma unroll
        for (int kt = 0; kt < 8; ++kt) {
            const short8 b = *(const short8*)(Wt + (size_t)c * 256 + kt * 32 + quad * 8);
            accA = __builtin_amdgcn_mfma_f32_16x16x32_bf16(aloA[kt], b, accA, 0, 0, 0);
            accA = __builtin_amdgcn_mfma_f32_16x16x32_bf16(ahiA[kt], b, accA, 0, 0, 0);
            accB = __builtin_amdgcn_mfma_f32_16x16x32_bf16(aloB[kt], b, accB, 0, 0, 0);
            accB = __builtin_amdgcn_mfma_f32_16x16x32_bf16(ahiB[kt], b, accB, 0, 0, 0);
        }
        const float bias = biascat[c];
        #pragma unroll
        for (int half = 0; half < 2; ++half) {
            const f32x4 acc = half ? accB : accA;
            #pragma unroll
            for (int i = 0; i < 4; ++i) {
                const int m = n0 + half * 16 + quad * 4 + i;   // D row
                if (m >= NNODES) continue;
                const float val = acc[i] + bias;
                if (c < 128)      Qb[(size_t)m * 128 + c] = f2bf(val);
                else if (c < 256) KVb[(size_t)m * 256 + (c - 128)] = f2bf(val);
                else if (c < 384) KVb[(size_t)m * 256 + 128 + (c - 256)] = f2bf(val);
                else              S[(size_t)m * 32 + (c - 384)] = val;
            }
        }
    }
}

// ---------------------------------------------------------------------------
// CSR build: histogram over dst, exclusive scan, scatter (src,w) by dst.
// ---------------------------------------------------------------------------
__global__ __launch_bounds__(256) void hist_kernel(
    const int* __restrict__ ei, int* __restrict__ cnt)
{
    const int e = blockIdx.x * 256 + threadIdx.x;
    if (e < NEDGES) atomicAdd(&cnt[ei[NEDGES + e]], 1);
}

#define CHUNK 49  // 49*1024 = 50176 >= 50000
__global__ __launch_bounds__(1024) void scan_kernel(
    const int* __restrict__ cnt, int* __restrict__ off, int* __restrict__ cursor)
{
    __shared__ int part[1024];
    const int t = threadIdx.x;
    const int base = t * CHUNK;
    int s = 0;
    #pragma unroll 7
    for (int i = 0; i < CHUNK; ++i) {
        const int idx = base + i;
        if (idx < NNODES) s += cnt[idx];
    }
    part[t] = s;
    __syncthreads();
    for (int d = 1; d < 1024; d <<= 1) {
        const int v = part[t];
        const int o = (t >= d) ? part[t - d] : 0;
        __syncthreads();
        part[t] = v + o;
        __syncthreads();
    }
    int run = (t == 0) ? 0 : part[t - 1];
    #pragma unroll 7
    for (int i = 0; i < CHUNK; ++i) {
        const int idx = base + i;
        if (idx < NNODES) {
            off[idx] = run;
            cursor[idx] = run;
            run += cnt[idx];
        }
    }
    if (t == 1023) off[NNODES] = run;
}

__global__ __launch_bounds__(256) void scatter_kernel(
    const int* __restrict__ ei, const float* __restrict__ ew,
    int* __restrict__ cursor, int2* __restrict__ einfo)
{
    const int e = blockIdx.x * 256 + threadIdx.x;
    if (e >= NEDGES) return;
    const int src = ei[e];
    const int dst = ei[NEDGES + e];
    const int pos = atomicAdd(&cursor[dst], 1);
    int2 v; v.x = src; v.y = __float_as_int(ew[e]);
    einfo[pos] = v;
}

// ---------------------------------------------------------------------------
// agg_pass: 32 lanes per node, bf16 gathers, rank-1 edge-attr decomposition:
//   alpha = (q.k)/sqrt(D) + w*(q.We)/sqrt(D) + (q.be)/sqrt(D)
//   agg   = [ sum p*v + (sum p*w)*We + (sum p)*be ] / (sum p + 1e-16)
// then head-mean -> G (N x 32 fp32).
// ---------------------------------------------------------------------------
__global__ __launch_bounds__(256) void agg_pass(
    const int* __restrict__ off, const int2* __restrict__ einfo,
    const float* __restrict__ We, const float* __restrict__ be,
    const unsigned short* __restrict__ Qb, const unsigned short* __restrict__ KVb,
    float* __restrict__ G)
{
    const int tid = threadIdx.x;
    const int node = blockIdx.x * 8 + (tid >> 5);
    if (node >= NNODES) return;
    const int l = tid & 31;          // 4 dims per lane; head = l>>3

    const float4 We4 = *(const float4*)(We + l * 4);
    const float4 be4 = *(const float4*)(be + l * 4);

    const ushort4 qu = *(const ushort4*)(Qb + (size_t)node * 128 + l * 4);
    const float q0 = bf2f(qu.x), q1 = bf2f(qu.y), q2 = bf2f(qu.z), q3 = bf2f(qu.w);

    // per-head q.We and q.be (uniform within each 8-lane head group after reduce)
    float pwe = q0 * We4.x + q1 * We4.y + q2 * We4.z + q3 * We4.w;
    float pbe = q0 * be4.x + q1 * be4.y + q2 * be4.z + q3 * be4.w;
    pwe += __shfl_xor(pwe, 1); pbe += __shfl_xor(pbe, 1);
    pwe += __shfl_xor(pwe, 2); pbe += __shfl_xor(pbe, 2);
    pwe += __shfl_xor(pwe, 4); pbe += __shfl_xor(pbe, 4);
    const float qWeS = pwe * RSQRT_D;
    const float qbeS = pbe * RSQRT_D;

    float a0 = 0.f, a1 = 0.f, a2 = 0.f, a3 = 0.f;
    float sp = 0.f, spw = 0.f;

    const int jb = off[node], je = off[node + 1];
    for (int j = jb; j < je; ++j) {
        const int2 einf = einfo[j];
        const int src = einf.x;
        const float w = __int_as_float(einf.y);
        const ushort4 ku = *(const ushort4*)(KVb + (size_t)src * 256 + l * 4);
        const ushort4 vu = *(const ushort4*)(KVb + (size_t)src * 256 + 128 + l * 4);

        float dot = q0 * bf2f(ku.x) + q1 * bf2f(ku.y)
                  + q2 * bf2f(ku.z) + q3 * bf2f(ku.w);
        dot += __shfl_xor(dot, 1);
        dot += __shfl_xor(dot, 2);
        dot += __shfl_xor(dot, 4);
        const float p = __expf(dot * RSQRT_D + w * qWeS + qbeS);
        sp += p; spw += p * w;
        a0 += p * bf2f(vu.x); a1 += p * bf2f(vu.y);
        a2 += p * bf2f(vu.z); a3 += p * bf2f(vu.w);
    }

    const float inv = 1.f / (sp + 1e-16f);
    a0 = (a0 + spw * We4.x + sp * be4.x) * inv;
    a1 = (a1 + spw * We4.y + sp * be4.y) * inv;
    a2 = (a2 + spw * We4.z + sp * be4.z) * inv;
    a3 = (a3 + spw * We4.w + sp * be4.w) * inv;

    // head mean: lanes l, l^8, l^16, l^24 hold the same within-head dim
    a0 += __shfl_xor(a0, 8);  a1 += __shfl_xor(a1, 8);
    a2 += __shfl_xor(a2, 8);  a3 += __shfl_xor(a3, 8);
    a0 += __shfl_xor(a0, 16); a1 += __shfl_xor(a1, 16);
    a2 += __shfl_xor(a2, 16); a3 += __shfl_xor(a3, 16);

    if (l < 8) {
        float4 g;
        g.x = a0 * 0.25f; g.y = a1 * 0.25f; g.z = a2 * 0.25f; g.w = a3 * 0.25f;
        *(float4*)(G + (size_t)node * 32 + l * 4) = g;
    }
}

// ---------------------------------------------------------------------------
// node_pass: y = tanh(G + S); z = tanh(y @ Wmlp + bmlp);
// out = x*z[:,:128] + z[:,128:]
// ---------------------------------------------------------------------------
__global__ __launch_bounds__(256) void node_pass(
    const float* __restrict__ x,
    const float* __restrict__ G, const float* __restrict__ S,
    const float* __restrict__ Wmlp, const float* __restrict__ bmlp,
    float* __restrict__ out)
{
    __shared__ float Wm[32 * 256];
    __shared__ float bm[256];
    __shared__ float yl[64 * 32];

    const int tid = threadIdx.x;
    for (int i = tid; i < 2048; i += 256)
        *(float4*)&Wm[i * 4] = *(const float4*)(Wmlp + i * 4);
    if (tid < 64)
        *(float4*)&bm[tid * 4] = *(const float4*)(bmlp + tid * 4);

    const int n0 = blockIdx.x * 64;

    for (int idx = tid; idx < 64 * 32; idx += 256) {
        const int nl = idx >> 5, d = idx & 31;
        const int n = n0 + nl;
        float yv = 0.f;
        if (n < NNODES)
            yv = tanhf(G[(size_t)n * 32 + d] + S[(size_t)n * 32 + d]);
        yl[idx] = yv;
    }
    __syncthreads();

    for (int idx = tid; idx < 64 * 128; idx += 256) {
        const int nl = idx >> 7, c = idx & 127;
        const int n = n0 + nl;
        if (n >= NNODES) continue;
        float s1 = bm[c], s2 = bm[c + 128];
        const float* yrow = &yl[nl * 32];
        #pragma unroll
        for (int d = 0; d < 32; ++d) {
            const float yv = yrow[d];
            s1 += yv * Wm[d * 256 + c];
            s2 += yv * Wm[d * 256 + c + 128];
        }
        out[(size_t)n * 128 + c] = x[(size_t)n * 128 + c] * tanhf(s1) + tanhf(s2);
    }
}

// ---------------------------------------------------------------------------
extern "C" void kernel_launch(void* const* d_in, const int* in_sizes, int n_in,
                              void* d_out, int out_size, void* d_ws, size_t ws_size,
                              hipStream_t stream) {
    const float* x     = (const float*)d_in[0];
    const float* t     = (const float*)d_in[1];
    const int*   ei    = (const int*)  d_in[2];
    const float* ew    = (const float*)d_in[3];
    const float* Wq    = (const float*)d_in[4];
    const float* bq    = (const float*)d_in[5];
    const float* Wk    = (const float*)d_in[6];
    const float* bk    = (const float*)d_in[7];
    const float* Wv    = (const float*)d_in[8];
    const float* bv    = (const float*)d_in[9];
    const float* We    = (const float*)d_in[10];
    const float* be    = (const float*)d_in[11];
    const float* Wskip = (const float*)d_in[12];
    const float* bskip = (const float*)d_in[13];
    const float* Wmlp  = (const float*)d_in[14];
    const float* bmlp  = (const float*)d_in[15];

    char* p = (char*)d_ws;
    unsigned short* Qb  = (unsigned short*)p; p += (size_t)NNODES * 128 * 2;
    unsigned short* KVb = (unsigned short*)p; p += (size_t)NNODES * 256 * 2;
    float* S       = (float*)p; p += (size_t)NNODES * 32 * 4;
    float* G       = (float*)p; p += (size_t)NNODES * 32 * 4;
    unsigned short* Wt = (unsigned short*)p; p += 416 * 256 * 2;
    float* biascat = (float*)p; p += 416 * 4;
    int2* einfo    = (int2*)p;  p += (size_t)NEDGES * 8;
    int* cnt       = (int*)p;   p += NNODES * 4;
    int* cursor    = (int*)p;   p += NNODES * 4;
    int* off       = (int*)p;   p += (NNODES + 1) * 4;

    hipMemsetAsync(cnt, 0, (size_t)NNODES * sizeof(int), stream);

    prep_w<<<416, 256, 0, stream>>>(Wq, bq, Wk, bk, Wv, bv, Wskip, bskip,
                                    Wt, biascat);

    hist_kernel<<<NEDGES / 256, 256, 0, stream>>>(ei, cnt);

    gemm_mfma<<<(NNODES + 127) / 128, 256, 0, stream>>>(x, t, Wt, biascat,
                                                        Qb, KVb, S);

    scan_kernel<<<1, 1024, 0, stream>>>(cnt, off, cursor);
    scatter_kernel<<<NEDGES / 256, 256, 0, stream>>>(ei, ew, cursor, einfo);

    agg_pass<<<NNODES / 8, 256, 0, stream>>>(off, einfo, We, be, Qb, KVb, G);

    node_pass<<<(NNODES + 63) / 64, 256, 0, stream>>>(x, G, S, Wmlp, bmlp,
                                                      (float*)d_out);
}

// Round 4
// 547.212 us; speedup vs baseline: 3.1544x; 1.0289x over previous
//
#include <hip/hip_runtime.h>
#include <hip/hip_bf16.h>

#define NNODES 50000
#define NEDGES 800000
#define RSQRT_D 0.17677669529663687f  // 1/sqrt(32)

typedef short short8 __attribute__((ext_vector_type(8)));   // 8 bf16 (4 VGPRs)
typedef float f32x4 __attribute__((ext_vector_type(4)));    // MFMA accumulator

__device__ inline unsigned short f2bf(float f) {
    union { float f; unsigned u; } v; v.f = f;
    unsigned r = (v.u + 0x7fff + ((v.u >> 16) & 1)) >> 16;   // round-to-nearest-even
    return (unsigned short)r;
}
__device__ inline float bf2f(unsigned short u) {
    union { unsigned u; float f; } v; v.u = ((unsigned)u) << 16;
    return v.f;
}

// ---------------------------------------------------------------------------
// prep_w: Wt[col][k] bf16 (col 0..415 = Q|K|V|skip), biascat[col] fp32.
// ---------------------------------------------------------------------------
__global__ __launch_bounds__(256) void prep_w(
    const float* __restrict__ Wq, const float* __restrict__ bq,
    const float* __restrict__ Wk, const float* __restrict__ bk,
    const float* __restrict__ Wv, const float* __restrict__ bv,
    const float* __restrict__ Wskip, const float* __restrict__ bskip,
    unsigned short* __restrict__ Wt, float* __restrict__ biascat)
{
    const int col = blockIdx.x;
    const int k = threadIdx.x;
    float v; float b;
    if (col < 128)      { v = Wq[k * 128 + col];          b = bq[col]; }
    else if (col < 256) { v = Wk[k * 128 + col - 128];    b = bk[col - 128]; }
    else if (col < 384) { v = Wv[k * 128 + col - 256];    b = bv[col - 256]; }
    else                { v = Wskip[k * 32 + col - 384];  b = bskip[col - 384]; }
    Wt[col * 256 + k] = f2bf(v);
    if (k == 0) biascat[col] = b;
}

// ---------------------------------------------------------------------------
// gemm_mfma: C[n][c] = y0[n][:] @ Wt[c][:] + bias, split-bf16 (hi+lo) MFMA.
// One wave per 16 rows (A-frags = 64 VGPRs); grid.y=2 splits the 26 col-tiles.
// 782x2 blocks x 4 waves -> ~24 waves/CU supply (latency fix vs R3's 8.5%).
// Outputs: Q bf16 [N][128], KV bf16 [N][256] (K|V), S fp32 [N][32].
// ---------------------------------------------------------------------------
__global__ __launch_bounds__(256) void gemm_mfma(
    const float* __restrict__ x, const float* __restrict__ t,
    const unsigned short* __restrict__ Wt, const float* __restrict__ biascat,
    unsigned short* __restrict__ Qb, unsigned short* __restrict__ KVb,
    float* __restrict__ S)
{
    const int tid = threadIdx.x;
    const int wave = tid >> 6;
    const int lane = tid & 63;
    const int row16 = lane & 15;
    const int quad = lane >> 4;

    const int n0 = blockIdx.x * 64 + wave * 16;    // 16 rows per wave
    const int row = n0 + row16;
    const int ct0 = blockIdx.y * 13;               // 13 col-tiles per block

    short8 ahi[8], alo[8];

    // Load this wave's A fragments once (y0 = [x, x*t] on the fly).
    // A[m][k]: m = row16, k = quad*8 + j (j=0..7), per kt-tile of 32.
    #pragma unroll
    for (int kt = 0; kt < 8; ++kt) {
        const int kk = kt * 32 + quad * 8;
        const int kx = (kk < 128) ? kk : (kk - 128);
        float4 f0 = make_float4(0, 0, 0, 0), f1 = f0;
        if (row < NNODES) {
            const float* xr = x + (size_t)row * 128 + kx;
            f0 = *(const float4*)xr;
            f1 = *(const float4*)(xr + 4);
            if (kk >= 128) {
                const float tv = t[row];
                f0.x *= tv; f0.y *= tv; f0.z *= tv; f0.w *= tv;
                f1.x *= tv; f1.y *= tv; f1.z *= tv; f1.w *= tv;
            }
        }
        float fv[8] = { f0.x, f0.y, f0.z, f0.w, f1.x, f1.y, f1.z, f1.w };
        short8 hi, lo;
        #pragma unroll
        for (int j = 0; j < 8; ++j) {
            const unsigned short h = f2bf(fv[j]);
            hi[j] = (short)h;
            lo[j] = (short)f2bf(fv[j] - bf2f(h));
        }
        ahi[kt] = hi; alo[kt] = lo;
    }

    for (int ct = ct0; ct < ct0 + 13; ++ct) {
        const int c = ct * 16 + row16;             // B col / D col for this lane
        f32x4 acc = {0.f, 0.f, 0.f, 0.f};
        #pragma unroll
        for (int kt = 0; kt < 8; ++kt) {
            const short8 b = *(const short8*)(Wt + (size_t)c * 256 + kt * 32 + quad * 8);
            acc = __builtin_amdgcn_mfma_f32_16x16x32_bf16(alo[kt], b, acc, 0, 0, 0);
            acc = __builtin_amdgcn_mfma_f32_16x16x32_bf16(ahi[kt], b, acc, 0, 0, 0);
        }
        const float bias = biascat[c];
        // D: col = row16 (== c), row = quad*4 + i. Branch is wave-uniform
        // (16-col tiles never straddle the 128/256/384 boundaries).
        #pragma unroll
        for (int i = 0; i < 4; ++i) {
            const int m = n0 + quad * 4 + i;
            if (m >= NNODES) continue;
            const float val = acc[i] + bias;
            if (c < 128)      Qb[(size_t)m * 128 + c] = f2bf(val);
            else if (c < 256) KVb[(size_t)m * 256 + (c - 128)] = f2bf(val);
            else if (c < 384) KVb[(size_t)m * 256 + 128 + (c - 256)] = f2bf(val);
            else              S[(size_t)m * 32 + (c - 384)] = val;
        }
    }
}

// ---------------------------------------------------------------------------
// CSR build: histogram over dst, exclusive scan, scatter (src,w) by dst.
// ---------------------------------------------------------------------------
__global__ __launch_bounds__(256) void hist_kernel(
    const int* __restrict__ ei, int* __restrict__ cnt)
{
    const int e = blockIdx.x * 256 + threadIdx.x;
    if (e < NEDGES) atomicAdd(&cnt[ei[NEDGES + e]], 1);
}

#define CHUNK 49  // 49*1024 = 50176 >= 50000
__global__ __launch_bounds__(1024) void scan_kernel(
    const int* __restrict__ cnt, int* __restrict__ off, int* __restrict__ cursor)
{
    __shared__ int part[1024];
    const int t = threadIdx.x;
    const int base = t * CHUNK;
    int s = 0;
    #pragma unroll 7
    for (int i = 0; i < CHUNK; ++i) {
        const int idx = base + i;
        if (idx < NNODES) s += cnt[idx];
    }
    part[t] = s;
    __syncthreads();
    for (int d = 1; d < 1024; d <<= 1) {
        const int v = part[t];
        const int o = (t >= d) ? part[t - d] : 0;
        __syncthreads();
        part[t] = v + o;
        __syncthreads();
    }
    int run = (t == 0) ? 0 : part[t - 1];
    #pragma unroll 7
    for (int i = 0; i < CHUNK; ++i) {
        const int idx = base + i;
        if (idx < NNODES) {
            off[idx] = run;
            cursor[idx] = run;
            run += cnt[idx];
        }
    }
    if (t == 1023) off[NNODES] = run;
}

__global__ __launch_bounds__(256) void scatter_kernel(
    const int* __restrict__ ei, const float* __restrict__ ew,
    int* __restrict__ cursor, int2* __restrict__ einfo)
{
    const int e = blockIdx.x * 256 + threadIdx.x;
    if (e >= NEDGES) return;
    const int src = ei[e];
    const int dst = ei[NEDGES + e];
    const int pos = atomicAdd(&cursor[dst], 1);
    int2 v; v.x = src; v.y = __float_as_int(ew[e]);
    einfo[pos] = v;
}

// ---------------------------------------------------------------------------
// agg_pass: 32 lanes per node, bf16 gathers, rank-1 edge-attr decomposition:
//   alpha = (q.k)/sqrt(D) + w*(q.We)/sqrt(D) + (q.be)/sqrt(D)
//   agg   = [ sum p*v + (sum p*w)*We + (sum p)*be ] / (sum p + 1e-16)
// then head-mean -> G (N x 32 fp32).
// ---------------------------------------------------------------------------
__global__ __launch_bounds__(256) void agg_pass(
    const int* __restrict__ off, const int2* __restrict__ einfo,
    const float* __restrict__ We, const float* __restrict__ be,
    const unsigned short* __restrict__ Qb, const unsigned short* __restrict__ KVb,
    float* __restrict__ G)
{
    const int tid = threadIdx.x;
    const int node = blockIdx.x * 8 + (tid >> 5);
    if (node >= NNODES) return;
    const int l = tid & 31;          // 4 dims per lane; head = l>>3

    const float4 We4 = *(const float4*)(We + l * 4);
    const float4 be4 = *(const float4*)(be + l * 4);

    const ushort4 qu = *(const ushort4*)(Qb + (size_t)node * 128 + l * 4);
    const float q0 = bf2f(qu.x), q1 = bf2f(qu.y), q2 = bf2f(qu.z), q3 = bf2f(qu.w);

    float pwe = q0 * We4.x + q1 * We4.y + q2 * We4.z + q3 * We4.w;
    float pbe = q0 * be4.x + q1 * be4.y + q2 * be4.z + q3 * be4.w;
    pwe += __shfl_xor(pwe, 1); pbe += __shfl_xor(pbe, 1);
    pwe += __shfl_xor(pwe, 2); pbe += __shfl_xor(pbe, 2);
    pwe += __shfl_xor(pwe, 4); pbe += __shfl_xor(pbe, 4);
    const float qWeS = pwe * RSQRT_D;
    const float qbeS = pbe * RSQRT_D;

    float a0 = 0.f, a1 = 0.f, a2 = 0.f, a3 = 0.f;
    float sp = 0.f, spw = 0.f;

    const int jb = off[node], je = off[node + 1];
    for (int j = jb; j < je; ++j) {
        const int2 einf = einfo[j];
        const int src = einf.x;
        const float w = __int_as_float(einf.y);
        const ushort4 ku = *(const ushort4*)(KVb + (size_t)src * 256 + l * 4);
        const ushort4 vu = *(const ushort4*)(KVb + (size_t)src * 256 + 128 + l * 4);

        float dot = q0 * bf2f(ku.x) + q1 * bf2f(ku.y)
                  + q2 * bf2f(ku.z) + q3 * bf2f(ku.w);
        dot += __shfl_xor(dot, 1);
        dot += __shfl_xor(dot, 2);
        dot += __shfl_xor(dot, 4);
        const float p = __expf(dot * RSQRT_D + w * qWeS + qbeS);
        sp += p; spw += p * w;
        a0 += p * bf2f(vu.x); a1 += p * bf2f(vu.y);
        a2 += p * bf2f(vu.z); a3 += p * bf2f(vu.w);
    }

    const float inv = 1.f / (sp + 1e-16f);
    a0 = (a0 + spw * We4.x + sp * be4.x) * inv;
    a1 = (a1 + spw * We4.y + sp * be4.y) * inv;
    a2 = (a2 + spw * We4.z + sp * be4.z) * inv;
    a3 = (a3 + spw * We4.w + sp * be4.w) * inv;

    a0 += __shfl_xor(a0, 8);  a1 += __shfl_xor(a1, 8);
    a2 += __shfl_xor(a2, 8);  a3 += __shfl_xor(a3, 8);
    a0 += __shfl_xor(a0, 16); a1 += __shfl_xor(a1, 16);
    a2 += __shfl_xor(a2, 16); a3 += __shfl_xor(a3, 16);

    if (l < 8) {
        float4 g;
        g.x = a0 * 0.25f; g.y = a1 * 0.25f; g.z = a2 * 0.25f; g.w = a3 * 0.25f;
        *(float4*)(G + (size_t)node * 32 + l * 4) = g;
    }
}

// ---------------------------------------------------------------------------
// node_pass: y = tanh(G + S); z = tanh(y @ Wmlp + bmlp);
// out = x*z[:,:128] + z[:,128:]
// ---------------------------------------------------------------------------
__global__ __launch_bounds__(256) void node_pass(
    const float* __restrict__ x,
    const float* __restrict__ G, const float* __restrict__ S,
    const float* __restrict__ Wmlp, const float* __restrict__ bmlp,
    float* __restrict__ out)
{
    __shared__ float Wm[32 * 256];
    __shared__ float bm[256];
    __shared__ float yl[64 * 32];

    const int tid = threadIdx.x;
    for (int i = tid; i < 2048; i += 256)
        *(float4*)&Wm[i * 4] = *(const float4*)(Wmlp + i * 4);
    if (tid < 64)
        *(float4*)&bm[tid * 4] = *(const float4*)(bmlp + tid * 4);

    const int n0 = blockIdx.x * 64;

    for (int idx = tid; idx < 64 * 32; idx += 256) {
        const int nl = idx >> 5, d = idx & 31;
        const int n = n0 + nl;
        float yv = 0.f;
        if (n < NNODES)
            yv = tanhf(G[(size_t)n * 32 + d] + S[(size_t)n * 32 + d]);
        yl[idx] = yv;
    }
    __syncthreads();

    for (int idx = tid; idx < 64 * 128; idx += 256) {
        const int nl = idx >> 7, c = idx & 127;
        const int n = n0 + nl;
        if (n >= NNODES) continue;
        float s1 = bm[c], s2 = bm[c + 128];
        const float* yrow = &yl[nl * 32];
        #pragma unroll
        for (int d = 0; d < 32; ++d) {
            const float yv = yrow[d];
            s1 += yv * Wm[d * 256 + c];
            s2 += yv * Wm[d * 256 + c + 128];
        }
        out[(size_t)n * 128 + c] = x[(size_t)n * 128 + c] * tanhf(s1) + tanhf(s2);
    }
}

// ---------------------------------------------------------------------------
extern "C" void kernel_launch(void* const* d_in, const int* in_sizes, int n_in,
                              void* d_out, int out_size, void* d_ws, size_t ws_size,
                              hipStream_t stream) {
    const float* x     = (const float*)d_in[0];
    const float* t     = (const float*)d_in[1];
    const int*   ei    = (const int*)  d_in[2];
    const float* ew    = (const float*)d_in[3];
    const float* Wq    = (const float*)d_in[4];
    const float* bq    = (const float*)d_in[5];
    const float* Wk    = (const float*)d_in[6];
    const float* bk    = (const float*)d_in[7];
    const float* Wv    = (const float*)d_in[8];
    const float* bv    = (const float*)d_in[9];
    const float* We    = (const float*)d_in[10];
    const float* be    = (const float*)d_in[11];
    const float* Wskip = (const float*)d_in[12];
    const float* bskip = (const float*)d_in[13];
    const float* Wmlp  = (const float*)d_in[14];
    const float* bmlp  = (const float*)d_in[15];

    char* p = (char*)d_ws;
    unsigned short* Qb  = (unsigned short*)p; p += (size_t)NNODES * 128 * 2;
    unsigned short* KVb = (unsigned short*)p; p += (size_t)NNODES * 256 * 2;
    float* S       = (float*)p; p += (size_t)NNODES * 32 * 4;
    float* G       = (float*)p; p += (size_t)NNODES * 32 * 4;
    unsigned short* Wt = (unsigned short*)p; p += 416 * 256 * 2;
    float* biascat = (float*)p; p += 416 * 4;
    int2* einfo    = (int2*)p;  p += (size_t)NEDGES * 8;
    int* cnt       = (int*)p;   p += NNODES * 4;
    int* cursor    = (int*)p;   p += NNODES * 4;
    int* off       = (int*)p;   p += (NNODES + 1) * 4;

    hipMemsetAsync(cnt, 0, (size_t)NNODES * sizeof(int), stream);

    prep_w<<<416, 256, 0, stream>>>(Wq, bq, Wk, bk, Wv, bv, Wskip, bskip,
                                    Wt, biascat);

    hist_kernel<<<NEDGES / 256, 256, 0, stream>>>(ei, cnt);

    dim3 gg((NNODES + 63) / 64, 2);
    gemm_mfma<<<gg, 256, 0, stream>>>(x, t, Wt, biascat, Qb, KVb, S);

    scan_kernel<<<1, 1024, 0, stream>>>(cnt, off, cursor);
    scatter_kernel<<<NEDGES / 256, 256, 0, stream>>>(ei, ew, cursor, einfo);

    agg_pass<<<NNODES / 8, 256, 0, stream>>>(off, einfo, We, be, Qb, KVb, G);

    node_pass<<<(NNODES + 63) / 64, 256, 0, stream>>>(x, G, S, Wmlp, bmlp,
                                                      (float*)d_out);
}

// Round 5
// 385.686 us; speedup vs baseline: 4.4754x; 1.4188x over previous
//
#include <hip/hip_runtime.h>
#include <hip/hip_bf16.h>

#define NNODES 50000
#define NEDGES 800000
#define CAP 64                       // padded-CSR capacity (max degree ~45, Poisson(16))
#define RSQRT_D 0.17677669529663687f // 1/sqrt(32)

typedef short short8 __attribute__((ext_vector_type(8)));   // 8 bf16 (4 VGPRs)
typedef float f32x4 __attribute__((ext_vector_type(4)));    // MFMA accumulator

__device__ inline unsigned short f2bf(float f) {
    union { float f; unsigned u; } v; v.f = f;
    unsigned r = (v.u + 0x7fff + ((v.u >> 16) & 1)) >> 16;   // round-to-nearest-even
    return (unsigned short)r;
}
__device__ inline float bf2f(unsigned short u) {
    union { unsigned u; float f; } v; v.u = ((unsigned)u) << 16;
    return v.f;
}

// ---------------------------------------------------------------------------
// prep_w: Wt[col][k] bf16 (col 0..415 = Q|K|V|skip), biascat[col] fp32.
// ---------------------------------------------------------------------------
__global__ __launch_bounds__(256) void prep_w(
    const float* __restrict__ Wq, const float* __restrict__ bq,
    const float* __restrict__ Wk, const float* __restrict__ bk,
    const float* __restrict__ Wv, const float* __restrict__ bv,
    const float* __restrict__ Wskip, const float* __restrict__ bskip,
    unsigned short* __restrict__ Wt, float* __restrict__ biascat)
{
    const int col = blockIdx.x;
    const int k = threadIdx.x;
    float v; float b;
    if (col < 128)      { v = Wq[k * 128 + col];          b = bq[col]; }
    else if (col < 256) { v = Wk[k * 128 + col - 128];    b = bk[col - 128]; }
    else if (col < 384) { v = Wv[k * 128 + col - 256];    b = bv[col - 256]; }
    else                { v = Wskip[k * 32 + col - 384];  b = bskip[col - 384]; }
    Wt[col * 256 + k] = f2bf(v);
    if (k == 0) biascat[col] = b;
}

// ---------------------------------------------------------------------------
// gemm_mfma: C[n][c] = y0[n][:] @ Wt[c][:] + bias, split-bf16 (hi+lo) MFMA.
// One wave per 16 rows; grid.y=2 splits the 26 col-tiles (occupancy fix, R4).
// Outputs: Q bf16 [N][128], KV bf16 [N][256] (K|V), S fp32 [N][32].
// ---------------------------------------------------------------------------
__global__ __launch_bounds__(256) void gemm_mfma(
    const float* __restrict__ x, const float* __restrict__ t,
    const unsigned short* __restrict__ Wt, const float* __restrict__ biascat,
    unsigned short* __restrict__ Qb, unsigned short* __restrict__ KVb,
    float* __restrict__ S)
{
    const int tid = threadIdx.x;
    const int wave = tid >> 6;
    const int lane = tid & 63;
    const int row16 = lane & 15;
    const int quad = lane >> 4;

    const int n0 = blockIdx.x * 64 + wave * 16;    // 16 rows per wave
    const int row = n0 + row16;
    const int ct0 = blockIdx.y * 13;               // 13 col-tiles per block

    short8 ahi[8], alo[8];

    #pragma unroll
    for (int kt = 0; kt < 8; ++kt) {
        const int kk = kt * 32 + quad * 8;
        const int kx = (kk < 128) ? kk : (kk - 128);
        float4 f0 = make_float4(0, 0, 0, 0), f1 = f0;
        if (row < NNODES) {
            const float* xr = x + (size_t)row * 128 + kx;
            f0 = *(const float4*)xr;
            f1 = *(const float4*)(xr + 4);
            if (kk >= 128) {
                const float tv = t[row];
                f0.x *= tv; f0.y *= tv; f0.z *= tv; f0.w *= tv;
                f1.x *= tv; f1.y *= tv; f1.z *= tv; f1.w *= tv;
            }
        }
        float fv[8] = { f0.x, f0.y, f0.z, f0.w, f1.x, f1.y, f1.z, f1.w };
        short8 hi, lo;
        #pragma unroll
        for (int j = 0; j < 8; ++j) {
            const unsigned short h = f2bf(fv[j]);
            hi[j] = (short)h;
            lo[j] = (short)f2bf(fv[j] - bf2f(h));
        }
        ahi[kt] = hi; alo[kt] = lo;
    }

    for (int ct = ct0; ct < ct0 + 13; ++ct) {
        const int c = ct * 16 + row16;             // B col / D col for this lane
        f32x4 acc = {0.f, 0.f, 0.f, 0.f};
        #pragma unroll
        for (int kt = 0; kt < 8; ++kt) {
            const short8 b = *(const short8*)(Wt + (size_t)c * 256 + kt * 32 + quad * 8);
            acc = __builtin_amdgcn_mfma_f32_16x16x32_bf16(alo[kt], b, acc, 0, 0, 0);
            acc = __builtin_amdgcn_mfma_f32_16x16x32_bf16(ahi[kt], b, acc, 0, 0, 0);
        }
        const float bias = biascat[c];
        #pragma unroll
        for (int i = 0; i < 4; ++i) {
            const int m = n0 + quad * 4 + i;
            if (m >= NNODES) continue;
            const float val = acc[i] + bias;
            if (c < 128)      Qb[(size_t)m * 128 + c] = f2bf(val);
            else if (c < 256) KVb[(size_t)m * 256 + (c - 128)] = f2bf(val);
            else if (c < 384) KVb[(size_t)m * 256 + 128 + (c - 256)] = f2bf(val);
            else              S[(size_t)m * 32 + (c - 384)] = val;
        }
    }
}

// ---------------------------------------------------------------------------
// scatter_fill: padded CSR in ONE pass — no histogram, no prefix scan.
// einfo[dst*CAP + pos] = (src, w); cnt[dst] = degree.
// ---------------------------------------------------------------------------
__global__ __launch_bounds__(256) void scatter_fill(
    const int* __restrict__ ei, const float* __restrict__ ew,
    int* __restrict__ cnt, int2* __restrict__ einfo)
{
    const int e = blockIdx.x * 256 + threadIdx.x;
    if (e >= NEDGES) return;
    const int src = ei[e];
    const int dst = ei[NEDGES + e];
    const int pos = atomicAdd(&cnt[dst], 1);
    if (pos < CAP) {
        int2 v; v.x = src; v.y = __float_as_int(ew[e]);
        einfo[(size_t)dst * CAP + pos] = v;
    }
}

// ---------------------------------------------------------------------------
// agg_pass: 32 lanes per node, bf16 gathers, rank-1 edge-attr decomposition:
//   alpha = (q.k)/sqrt(D) + w*(q.We)/sqrt(D) + (q.be)/sqrt(D)
//   agg   = [ sum p*v + (sum p*w)*We + (sum p)*be ] / (sum p + 1e-16)
// then head-mean -> G (N x 32 fp32).
// ---------------------------------------------------------------------------
__global__ __launch_bounds__(256) void agg_pass(
    const int* __restrict__ cnt, const int2* __restrict__ einfo,
    const float* __restrict__ We, const float* __restrict__ be,
    const unsigned short* __restrict__ Qb, const unsigned short* __restrict__ KVb,
    float* __restrict__ G)
{
    const int tid = threadIdx.x;
    const int node = blockIdx.x * 8 + (tid >> 5);
    if (node >= NNODES) return;
    const int l = tid & 31;          // 4 dims per lane; head = l>>3

    const float4 We4 = *(const float4*)(We + l * 4);
    const float4 be4 = *(const float4*)(be + l * 4);

    const ushort4 qu = *(const ushort4*)(Qb + (size_t)node * 128 + l * 4);
    const float q0 = bf2f(qu.x), q1 = bf2f(qu.y), q2 = bf2f(qu.z), q3 = bf2f(qu.w);

    float pwe = q0 * We4.x + q1 * We4.y + q2 * We4.z + q3 * We4.w;
    float pbe = q0 * be4.x + q1 * be4.y + q2 * be4.z + q3 * be4.w;
    pwe += __shfl_xor(pwe, 1); pbe += __shfl_xor(pbe, 1);
    pwe += __shfl_xor(pwe, 2); pbe += __shfl_xor(pbe, 2);
    pwe += __shfl_xor(pwe, 4); pbe += __shfl_xor(pbe, 4);
    const float qWeS = pwe * RSQRT_D;
    const float qbeS = pbe * RSQRT_D;

    float a0 = 0.f, a1 = 0.f, a2 = 0.f, a3 = 0.f;
    float sp = 0.f, spw = 0.f;

    const int deg = min(cnt[node], CAP);
    const int2* ep = einfo + (size_t)node * CAP;
    for (int j = 0; j < deg; ++j) {
        const int2 einf = ep[j];
        const int src = einf.x;
        const float w = __int_as_float(einf.y);
        const ushort4 ku = *(const ushort4*)(KVb + (size_t)src * 256 + l * 4);
        const ushort4 vu = *(const ushort4*)(KVb + (size_t)src * 256 + 128 + l * 4);

        float dot = q0 * bf2f(ku.x) + q1 * bf2f(ku.y)
                  + q2 * bf2f(ku.z) + q3 * bf2f(ku.w);
        dot += __shfl_xor(dot, 1);
        dot += __shfl_xor(dot, 2);
        dot += __shfl_xor(dot, 4);
        const float p = __expf(dot * RSQRT_D + w * qWeS + qbeS);
        sp += p; spw += p * w;
        a0 += p * bf2f(vu.x); a1 += p * bf2f(vu.y);
        a2 += p * bf2f(vu.z); a3 += p * bf2f(vu.w);
    }

    const float inv = 1.f / (sp + 1e-16f);
    a0 = (a0 + spw * We4.x + sp * be4.x) * inv;
    a1 = (a1 + spw * We4.y + sp * be4.y) * inv;
    a2 = (a2 + spw * We4.z + sp * be4.z) * inv;
    a3 = (a3 + spw * We4.w + sp * be4.w) * inv;

    a0 += __shfl_xor(a0, 8);  a1 += __shfl_xor(a1, 8);
    a2 += __shfl_xor(a2, 8);  a3 += __shfl_xor(a3, 8);
    a0 += __shfl_xor(a0, 16); a1 += __shfl_xor(a1, 16);
    a2 += __shfl_xor(a2, 16); a3 += __shfl_xor(a3, 16);

    if (l < 8) {
        float4 g;
        g.x = a0 * 0.25f; g.y = a1 * 0.25f; g.z = a2 * 0.25f; g.w = a3 * 0.25f;
        *(float4*)(G + (size_t)node * 32 + l * 4) = g;
    }
}

// ---------------------------------------------------------------------------
// node_pass: y = tanh(G + S); z = tanh(y @ Wmlp + bmlp);
// out = x*z[:,:128] + z[:,128:]
// ---------------------------------------------------------------------------
__global__ __launch_bounds__(256) void node_pass(
    const float* __restrict__ x,
    const float* __restrict__ G, const float* __restrict__ S,
    const float* __restrict__ Wmlp, const float* __restrict__ bmlp,
    float* __restrict__ out)
{
    __shared__ float Wm[32 * 256];
    __shared__ float bm[256];
    __shared__ float yl[64 * 32];

    const int tid = threadIdx.x;
    for (int i = tid; i < 2048; i += 256)
        *(float4*)&Wm[i * 4] = *(const float4*)(Wmlp + i * 4);
    if (tid < 64)
        *(float4*)&bm[tid * 4] = *(const float4*)(bmlp + tid * 4);

    const int n0 = blockIdx.x * 64;

    for (int idx = tid; idx < 64 * 32; idx += 256) {
        const int nl = idx >> 5, d = idx & 31;
        const int n = n0 + nl;
        float yv = 0.f;
        if (n < NNODES)
            yv = tanhf(G[(size_t)n * 32 + d] + S[(size_t)n * 32 + d]);
        yl[idx] = yv;
    }
    __syncthreads();

    for (int idx = tid; idx < 64 * 128; idx += 256) {
        const int nl = idx >> 7, c = idx & 127;
        const int n = n0 + nl;
        if (n >= NNODES) continue;
        float s1 = bm[c], s2 = bm[c + 128];
        const float* yrow = &yl[nl * 32];
        #pragma unroll
        for (int d = 0; d < 32; ++d) {
            const float yv = yrow[d];
            s1 += yv * Wm[d * 256 + c];
            s2 += yv * Wm[d * 256 + c + 128];
        }
        out[(size_t)n * 128 + c] = x[(size_t)n * 128 + c] * tanhf(s1) + tanhf(s2);
    }
}

// ---------------------------------------------------------------------------
extern "C" void kernel_launch(void* const* d_in, const int* in_sizes, int n_in,
                              void* d_out, int out_size, void* d_ws, size_t ws_size,
                              hipStream_t stream) {
    const float* x     = (const float*)d_in[0];
    const float* t     = (const float*)d_in[1];
    const int*   ei    = (const int*)  d_in[2];
    const float* ew    = (const float*)d_in[3];
    const float* Wq    = (const float*)d_in[4];
    const float* bq    = (const float*)d_in[5];
    const float* Wk    = (const float*)d_in[6];
    const float* bk    = (const float*)d_in[7];
    const float* Wv    = (const float*)d_in[8];
    const float* bv    = (const float*)d_in[9];
    const float* We    = (const float*)d_in[10];
    const float* be    = (const float*)d_in[11];
    const float* Wskip = (const float*)d_in[12];
    const float* bskip = (const float*)d_in[13];
    const float* Wmlp  = (const float*)d_in[14];
    const float* bmlp  = (const float*)d_in[15];

    char* p = (char*)d_ws;
    unsigned short* Qb  = (unsigned short*)p; p += (size_t)NNODES * 128 * 2;
    unsigned short* KVb = (unsigned short*)p; p += (size_t)NNODES * 256 * 2;
    float* S       = (float*)p; p += (size_t)NNODES * 32 * 4;
    float* G       = (float*)p; p += (size_t)NNODES * 32 * 4;
    unsigned short* Wt = (unsigned short*)p; p += 416 * 256 * 2;
    float* biascat = (float*)p; p += 416 * 4;
    int2* einfo    = (int2*)p;  p += (size_t)NNODES * CAP * 8;
    int* cnt       = (int*)p;   p += NNODES * 4;

    hipMemsetAsync(cnt, 0, (size_t)NNODES * sizeof(int), stream);

    prep_w<<<416, 256, 0, stream>>>(Wq, bq, Wk, bk, Wv, bv, Wskip, bskip,
                                    Wt, biascat);

    scatter_fill<<<NEDGES / 256, 256, 0, stream>>>(ei, ew, cnt, einfo);

    dim3 gg((NNODES + 63) / 64, 2);
    gemm_mfma<<<gg, 256, 0, stream>>>(x, t, Wt, biascat, Qb, KVb, S);

    agg_pass<<<NNODES / 8, 256, 0, stream>>>(cnt, einfo, We, be, Qb, KVb, G);

    node_pass<<<(NNODES + 63) / 64, 256, 0, stream>>>(x, G, S, Wmlp, bmlp,
                                                      (float*)d_out);
}